// Round 2
// baseline (603.258 us; speedup 1.0000x reference)
//
#include <hip/hip_runtime.h>
#include <stdint.h>

#define B_TOK 8192
#define DIN 1024
#define DHID 4096
#define DOUT 1024
#define NE 8

typedef __bf16 bf16x8 __attribute__((ext_vector_type(8)));
typedef float f32x4 __attribute__((ext_vector_type(4)));

__device__ __forceinline__ unsigned short f2bf(float f) {
  union { float f; unsigned u; } v; v.f = f;
  unsigned r = v.u + 0x7fffu + ((v.u >> 16) & 1u);  // RNE
  return (unsigned short)(r >> 16);
}

__device__ __forceinline__ void async16(const void* g, void* l) {
  __builtin_amdgcn_global_load_lds(
      (__attribute__((address_space(1))) void*)const_cast<void*>(g),
      (__attribute__((address_space(3))) void*)l, 16, 0, 0);
}

// ---------------- router: logits (fp64 acc), argmax, one-hot, x->bf16 ----------------
__global__ __launch_bounds__(256) void router_kernel(
    const float* __restrict__ x, const float* __restrict__ rw,
    const float* __restrict__ rb, float* __restrict__ oh,
    unsigned short* __restrict__ xb, int* __restrict__ idx,
    int* __restrict__ pos, int* __restrict__ counts)
{
  const int token = blockIdx.x * 4 + (threadIdx.x >> 6);
  const int lane = threadIdx.x & 63;
  const float* xrow = x + (size_t)token * DIN;
  double acc[NE];
#pragma unroll
  for (int e = 0; e < NE; ++e) acc[e] = 0.0;

#pragma unroll
  for (int j = 0; j < 4; ++j) {
    const int v4 = j * 64 + lane;                      // float4 index in row
    const float4 xv = ((const float4*)xrow)[v4];
    const float4* rwr = (const float4*)(rw + (size_t)v4 * 32);  // 4 rows x 8
#pragma unroll
    for (int c = 0; c < 4; ++c) {
      const float xs = (&xv.x)[c];
      const float4 w0 = rwr[c * 2 + 0];
      const float4 w1 = rwr[c * 2 + 1];
      acc[0] += (double)(xs * w0.x); acc[1] += (double)(xs * w0.y);
      acc[2] += (double)(xs * w0.z); acc[3] += (double)(xs * w0.w);
      acc[4] += (double)(xs * w1.x); acc[5] += (double)(xs * w1.y);
      acc[6] += (double)(xs * w1.z); acc[7] += (double)(xs * w1.w);
    }
    ushort4 us;
    us.x = f2bf(xv.x); us.y = f2bf(xv.y); us.z = f2bf(xv.z); us.w = f2bf(xv.w);
    ((ushort4*)(xb + (size_t)token * DIN))[v4] = us;
  }
#pragma unroll
  for (int off = 32; off > 0; off >>= 1)
#pragma unroll
    for (int e = 0; e < NE; ++e) acc[e] += __shfl_xor(acc[e], off, 64);

  if (lane == 0) {
    double best = -1e300; int be = 0;
#pragma unroll
    for (int e = 0; e < NE; ++e) {
      const double v = acc[e] + (double)rb[e];
      if (v > best) { best = v; be = e; }   // strict > == first-max (np argmax)
    }
    idx[token] = be;
    pos[token] = atomicAdd(&counts[be], 1);
    float* o = oh + (size_t)token * NE;
#pragma unroll
    for (int e = 0; e < NE; ++e) o[e] = (e == be) ? 1.f : 0.f;
  }
}

// ---------------- fp32 [K][N] -> bf16 [N][K] transpose-convert ----------------
__global__ __launch_bounds__(256) void transpose_bf16(
    const float* __restrict__ in, unsigned short* __restrict__ out, int K, int N)
{
  __shared__ float tile[64][65];
  const size_t mat = (size_t)blockIdx.z * (size_t)K * N;
  const int k0 = blockIdx.x * 64, n0 = blockIdx.y * 64;
  const int c = threadIdx.x & 63, r0 = threadIdx.x >> 6;
#pragma unroll
  for (int rr = 0; rr < 64; rr += 4)
    tile[rr + r0][c] = in[mat + (size_t)(k0 + rr + r0) * N + n0 + c];
  __syncthreads();
#pragma unroll
  for (int rr = 0; rr < 64; rr += 4) {
    const int n2 = rr + r0;
    out[mat + (size_t)(n0 + n2) * K + k0 + c] = f2bf(tile[c][n2]);
  }
}

// ---------------- tile schedule (single thread, trivial); M-tile = 256 ----------------
__global__ void slots_kernel(const int* __restrict__ counts, int* __restrict__ offsets,
                             int* __restrict__ slot_e, int* __restrict__ slot_g0,
                             int* __restrict__ slot_nr, int* __restrict__ nslots)
{
  int off = 0, s = 0;
  offsets[0] = 0;
  for (int e = 0; e < NE; ++e) {
    const int c = counts[e];
    for (int t = 0; t < c; t += 256) {
      slot_e[s] = e; slot_g0[s] = off + t;
      slot_nr[s] = (c - t < 256) ? (c - t) : 256;
      ++s;
    }
    off += c;
    offsets[e + 1] = off;
  }
  *nslots = s;
}

__global__ __launch_bounds__(256) void scatter_kernel(
    const int* __restrict__ idx, const int* __restrict__ pos,
    const int* __restrict__ offsets, int* __restrict__ perm)
{
  const int t = blockIdx.x * 256 + threadIdx.x;
  perm[offsets[idx[t]] + pos[t]] = t;
}

// ---------------- grouped expert GEMM: h[g] = x[perm[g]] @ W[e] + eb[e] ----------------
// BM=256, BN=128, BK=64; 512 threads = 8 waves (2M x 4N), per-wave 128x32.
// Phase-split K-pipeline with DERIVED counted waits (per-thread 6 loads/K-tile:
// A-h0=2, A-h1=2, B-h0=1, B-h1=1):
//   prologue: stage tile0 (6 loads)
//   B(t):  stage A-h0(t+1) [2] -> buf^1; vmcnt(2)  (= exactly tile t's 6 oldest
//          loads complete, A-h0(t+1) left in flight); s_barrier
//   P0:    ds_read ks0 frags; stage A-h1+B(t+1) [4]; barrier; lgkmcnt(0);
//          setprio(1); 16 MFMA; setprio(0); barrier
//   P1:    ds_read ks1 frags; barrier; lgkmcnt(0); 16 MFMA; barrier
// Loads span 2 phases + 1 boundary (~1400 cyc) before their wait; never vmcnt(0)
// except the final tile. Stage into a buffer only after the barrier ending the
// tile that last read it. Uniform load count (clamped A rows) keeps vmcnt
// accounting valid at partial tiles.
__global__ __launch_bounds__(512) void expert_gemm(
    const unsigned short* __restrict__ xb, const unsigned short* __restrict__ Wt,
    const float* __restrict__ eb, const int* __restrict__ perm,
    const int* __restrict__ slot_e, const int* __restrict__ slot_g0,
    const int* __restrict__ slot_nr, const int* __restrict__ nslots,
    unsigned short* __restrict__ h)
{
  const int id = blockIdx.x;
  const int s = id >> 5;           // slot (M-tile of 256 tokens)
  const int ntile = id & 31;       // 32 N-tiles of 128
  if (s >= *nslots) return;
  const int e = slot_e[s];
  const int g0 = slot_g0[s];
  const int nr = slot_nr[s];
  const int n0 = ntile * 128;

  __shared__ __align__(16) unsigned short lsA[2][256 * 64];   // 64 KB
  __shared__ __align__(16) unsigned short lsB[2][128 * 64];   // 32 KB

  const int tid = threadIdx.x;
  const int w = tid >> 6, lane = tid & 63;
  const int rgrp = lane >> 3, cch = lane & 7;
  const int sw8 = (cch ^ rgrp) * 8;          // XOR-swizzled global k-chunk
  const int wr = w >> 2, wc = w & 3;         // wave -> (2M x 4N)
  const int quad = lane >> 4, l15 = lane & 15;

  // A row sources: row(hh,l) = hh*128 + l*64 + w*8 + rgrp (clamped -> uniform count)
  const unsigned short* ap[4];
#pragma unroll
  for (int hh = 0; hh < 2; ++hh)
#pragma unroll
    for (int l = 0; l < 2; ++l) {
      const int row = hh * 128 + l * 64 + w * 8 + rgrp;
      ap[hh * 2 + l] = xb + (size_t)perm[g0 + (row < nr ? row : 0)] * DIN + sw8;
    }
  const unsigned short* wbp = Wt + (size_t)e * DHID * DIN;
  const unsigned short* bp[2];
#pragma unroll
  for (int hh = 0; hh < 2; ++hh)
    bp[hh] = wbp + (size_t)(n0 + hh * 64 + w * 8 + rgrp) * DIN + sw8;

  f32x4 acc[8][2];
  const f32x4 z = {0.f, 0.f, 0.f, 0.f};
#pragma unroll
  for (int i = 0; i < 8; ++i) { acc[i][0] = z; acc[i][1] = z; }

  auto stageA0 = [&](int db, int k0) {      // A half 0 (rows 0..127): 2 loads
    async16(ap[0] + k0, &lsA[db][(w * 8) * 64]);
    async16(ap[1] + k0, &lsA[db][(64 + w * 8) * 64]);
  };
  auto stageRest = [&](int db, int k0) {    // A half 1 + B both halves: 4 loads
    async16(ap[2] + k0, &lsA[db][(128 + w * 8) * 64]);
    async16(ap[3] + k0, &lsA[db][(192 + w * 8) * 64]);
    async16(bp[0] + k0, &lsB[db][(w * 8) * 64]);
    async16(bp[1] + k0, &lsB[db][(64 + w * 8) * 64]);
  };

  auto phase = [&](int db, int ks, bool dostage, int k0n) {
    bf16x8 af[8], bfv[2];
    const int q = ks * 4 + quad;
#pragma unroll
    for (int i = 0; i < 8; ++i) {
      const int row = wr * 128 + i * 16 + l15;
      af[i] = *(const bf16x8*)&lsA[db][row * 64 + ((q ^ (row & 7)) << 3)];
    }
#pragma unroll
    for (int j = 0; j < 2; ++j) {
      const int row = wc * 32 + j * 16 + l15;
      bfv[j] = *(const bf16x8*)&lsB[db][row * 64 + ((q ^ (row & 7)) << 3)];
    }
    if (dostage) stageRest(db ^ 1, k0n);
    __builtin_amdgcn_s_barrier();
    asm volatile("s_waitcnt lgkmcnt(0)" ::: "memory");
    __builtin_amdgcn_sched_barrier(0);           // rule #18: keep MFMA below wait
    __builtin_amdgcn_s_setprio(1);
#pragma unroll
    for (int i = 0; i < 8; ++i)
#pragma unroll
      for (int j = 0; j < 2; ++j)
        acc[i][j] = __builtin_amdgcn_mfma_f32_16x16x32_bf16(af[i], bfv[j], acc[i][j], 0, 0, 0);
    __builtin_amdgcn_s_setprio(0);
    __builtin_amdgcn_s_barrier();
  };

  auto tile = [&](int db, int t, bool notlast) {
    if (notlast) {
      stageA0(db ^ 1, (t + 1) * 64);
      asm volatile("s_waitcnt vmcnt(2)" ::: "memory");
    } else {
      asm volatile("s_waitcnt vmcnt(0)" ::: "memory");
    }
    __builtin_amdgcn_s_barrier();
    phase(db, 0, notlast, (t + 1) * 64);
    phase(db, 1, false, 0);
  };

  stageA0(0, 0);
  stageRest(0, 0);                     // full tile 0: 6 loads
  constexpr int NT = DIN / 64;         // 16 (even)
  for (int t = 0; t < NT; t += 2) {
    tile(0, t, true);                  // t <= NT-2 -> t+1 always exists
    tile(1, t + 1, t + 2 < NT);
  }

#pragma unroll
  for (int j = 0; j < 2; ++j) {
    const int col = n0 + wc * 32 + j * 16 + l15;
    const float bias = eb[e * DHID + col];
#pragma unroll
    for (int i = 0; i < 8; ++i)
#pragma unroll
      for (int r2 = 0; r2 < 4; ++r2) {
        const int row = wr * 128 + i * 16 + quad * 4 + r2;  // C/D: row=(lane>>4)*4+reg
        if (row < nr)
          h[(size_t)(g0 + row) * DHID + col] = f2bf(acc[i][j][r2] + bias);
      }
  }
}

// ---------------- projection GEMM: out[perm[g]] = h[g] @ P + pb ----------------
// BM=256, BN=128 -> grid 8 ntiles x 32 mtiles = 256 blocks (1/CU).
// id = ntile*32 + mtile: A(h)-tile sharers (same mtile, 8 ntiles) at id stride
// 32 == 0 mod 8 -> same XCD -> h read ~once from HBM. Same derived-wait pipeline.
__global__ __launch_bounds__(512) void proj_gemm(
    const unsigned short* __restrict__ hm, const unsigned short* __restrict__ Pt,
    const float* __restrict__ pb, const int* __restrict__ perm,
    float* __restrict__ out)
{
  const int id = blockIdx.x;
  const int m0 = (id & 31) * 256;
  const int n0 = (id >> 5) * 128;

  __shared__ __align__(16) unsigned short lsA[2][256 * 64];
  __shared__ __align__(16) unsigned short lsB[2][128 * 64];

  const int tid = threadIdx.x;
  const int w = tid >> 6, lane = tid & 63;
  const int rgrp = lane >> 3, cch = lane & 7;
  const int sw8 = (cch ^ rgrp) * 8;
  const int wr = w >> 2, wc = w & 3;
  const int quad = lane >> 4, l15 = lane & 15;

  const unsigned short* ap[4];
#pragma unroll
  for (int hh = 0; hh < 2; ++hh)
#pragma unroll
    for (int l = 0; l < 2; ++l) {
      const int row = m0 + hh * 128 + l * 64 + w * 8 + rgrp;
      ap[hh * 2 + l] = hm + (size_t)row * DHID + sw8;
    }
  const unsigned short* bp[2];
#pragma unroll
  for (int hh = 0; hh < 2; ++hh)
    bp[hh] = Pt + (size_t)(n0 + hh * 64 + w * 8 + rgrp) * DHID + sw8;

  f32x4 acc[8][2];
  const f32x4 z = {0.f, 0.f, 0.f, 0.f};
#pragma unroll
  for (int i = 0; i < 8; ++i) { acc[i][0] = z; acc[i][1] = z; }

  auto stageA0 = [&](int db, int k0) {
    async16(ap[0] + k0, &lsA[db][(w * 8) * 64]);
    async16(ap[1] + k0, &lsA[db][(64 + w * 8) * 64]);
  };
  auto stageRest = [&](int db, int k0) {
    async16(ap[2] + k0, &lsA[db][(128 + w * 8) * 64]);
    async16(ap[3] + k0, &lsA[db][(192 + w * 8) * 64]);
    async16(bp[0] + k0, &lsB[db][(w * 8) * 64]);
    async16(bp[1] + k0, &lsB[db][(64 + w * 8) * 64]);
  };

  auto phase = [&](int db, int ks, bool dostage, int k0n) {
    bf16x8 af[8], bfv[2];
    const int q = ks * 4 + quad;
#pragma unroll
    for (int i = 0; i < 8; ++i) {
      const int row = wr * 128 + i * 16 + l15;
      af[i] = *(const bf16x8*)&lsA[db][row * 64 + ((q ^ (row & 7)) << 3)];
    }
#pragma unroll
    for (int j = 0; j < 2; ++j) {
      const int row = wc * 32 + j * 16 + l15;
      bfv[j] = *(const bf16x8*)&lsB[db][row * 64 + ((q ^ (row & 7)) << 3)];
    }
    if (dostage) stageRest(db ^ 1, k0n);
    __builtin_amdgcn_s_barrier();
    asm volatile("s_waitcnt lgkmcnt(0)" ::: "memory");
    __builtin_amdgcn_sched_barrier(0);
    __builtin_amdgcn_s_setprio(1);
#pragma unroll
    for (int i = 0; i < 8; ++i)
#pragma unroll
      for (int j = 0; j < 2; ++j)
        acc[i][j] = __builtin_amdgcn_mfma_f32_16x16x32_bf16(af[i], bfv[j], acc[i][j], 0, 0, 0);
    __builtin_amdgcn_s_setprio(0);
    __builtin_amdgcn_s_barrier();
  };

  auto tile = [&](int db, int t, bool notlast) {
    if (notlast) {
      stageA0(db ^ 1, (t + 1) * 64);
      asm volatile("s_waitcnt vmcnt(2)" ::: "memory");
    } else {
      asm volatile("s_waitcnt vmcnt(0)" ::: "memory");
    }
    __builtin_amdgcn_s_barrier();
    phase(db, 0, notlast, (t + 1) * 64);
    phase(db, 1, false, 0);
  };

  stageA0(0, 0);
  stageRest(0, 0);
  constexpr int NT = DHID / 64;        // 64 (even)
  for (int t = 0; t < NT; t += 2) {
    tile(0, t, true);
    tile(1, t + 1, t + 2 < NT);
  }

#pragma unroll
  for (int i = 0; i < 8; ++i)
#pragma unroll
    for (int r2 = 0; r2 < 4; ++r2) {
      const int row = m0 + wr * 128 + i * 16 + quad * 4 + r2;
      const int orow = perm[row];
#pragma unroll
      for (int j = 0; j < 2; ++j) {
        const int col = n0 + wc * 32 + j * 16 + l15;
        out[(size_t)orow * DOUT + col] = acc[i][j][r2] + pb[col];
      }
    }
}

extern "C" void kernel_launch(void* const* d_in, const int* in_sizes, int n_in,
                              void* d_out, int out_size, void* d_ws, size_t ws_size,
                              hipStream_t stream)
{
  const float* x  = (const float*)d_in[0];
  const float* rw = (const float*)d_in[1];
  const float* rb = (const float*)d_in[2];
  const float* ew = (const float*)d_in[3];
  const float* eb = (const float*)d_in[4];
  const float* pw = (const float*)d_in[5];
  const float* pb = (const float*)d_in[6];
  float* out = (float*)d_out;
  float* oh  = out + (size_t)B_TOK * DOUT;   // one-hot routing weights tail

  char* ws = (char*)d_ws;
  constexpr size_t OXB = 0;                                         // x bf16 [8192][1024]
  constexpr size_t OWT = OXB + (size_t)B_TOK * DIN * 2;             // W^T bf16 [8][4096][1024]
  constexpr size_t OPT = OWT + (size_t)NE * DHID * DIN * 2;         // P^T bf16 [1024][4096]
  constexpr size_t OH  = OPT + (size_t)DOUT * DHID * 2;             // h bf16 [8192][4096] (perm order)
  constexpr size_t OIDX = OH + (size_t)B_TOK * DHID * 2;
  constexpr size_t OPOS = OIDX + (size_t)B_TOK * 4;
  constexpr size_t OPRM = OPOS + (size_t)B_TOK * 4;
  constexpr size_t OCNT = OPRM + (size_t)B_TOK * 4;
  constexpr size_t OOFF = OCNT + 256;
  constexpr size_t OSE  = OOFF + 256;
  constexpr size_t OSG  = OSE + 512;
  constexpr size_t OSN  = OSG + 512;
  constexpr size_t ONS  = OSN + 512;
  constexpr size_t NEED = ONS + 512;

  // Workspace guard: fail cleanly (zeroed output) instead of faulting.
  if (ws_size < NEED) {
    hipMemsetAsync(d_out, 0, (size_t)out_size * 4, stream);
    return;
  }

  unsigned short* xb   = (unsigned short*)(ws + OXB);
  unsigned short* Wt   = (unsigned short*)(ws + OWT);
  unsigned short* Pt   = (unsigned short*)(ws + OPT);
  unsigned short* h    = (unsigned short*)(ws + OH);
  int* idx     = (int*)(ws + OIDX);
  int* pos     = (int*)(ws + OPOS);
  int* perm    = (int*)(ws + OPRM);
  int* counts  = (int*)(ws + OCNT);
  int* offsets = (int*)(ws + OOFF);
  int* slot_e  = (int*)(ws + OSE);
  int* slot_g0 = (int*)(ws + OSG);
  int* slot_nr = (int*)(ws + OSN);
  int* nslots  = (int*)(ws + ONS);

  hipMemsetAsync(counts, 0, 64, stream);
  router_kernel<<<B_TOK / 4, 256, 0, stream>>>(x, rw, rb, oh, xb, idx, pos, counts);
  transpose_bf16<<<dim3(DIN / 64, DHID / 64, NE), 256, 0, stream>>>(ew, Wt, DIN, DHID);
  transpose_bf16<<<dim3(DHID / 64, DOUT / 64, 1), 256, 0, stream>>>(pw, Pt, DHID, DOUT);
  slots_kernel<<<1, 1, 0, stream>>>(counts, offsets, slot_e, slot_g0, slot_nr, nslots);
  scatter_kernel<<<B_TOK / 256, 256, 0, stream>>>(idx, pos, offsets, perm);
  // 40 slot capacity (32 full 256-row tiles + up to 7 expert-boundary partials, padded)
  expert_gemm<<<40 * 32, 512, 0, stream>>>(
      xb, Wt, eb, perm, slot_e, slot_g0, slot_nr, nslots, h);
  proj_gemm<<<(DOUT / 128) * (B_TOK / 256), 512, 0, stream>>>(h, Pt, pb, perm, out);
}

// Round 3
// 585.341 us; speedup vs baseline: 1.0306x; 1.0306x over previous
//
#include <hip/hip_runtime.h>
#include <stdint.h>

#define B_TOK 8192
#define DIN 1024
#define DHID 4096
#define DOUT 1024
#define NE 8

typedef __bf16 bf16x8 __attribute__((ext_vector_type(8)));
typedef float f32x4 __attribute__((ext_vector_type(4)));

__device__ __forceinline__ unsigned short f2bf(float f) {
  union { float f; unsigned u; } v; v.f = f;
  unsigned r = v.u + 0x7fffu + ((v.u >> 16) & 1u);  // RNE
  return (unsigned short)(r >> 16);
}

__device__ __forceinline__ void async16(const void* g, void* l) {
  __builtin_amdgcn_global_load_lds(
      (__attribute__((address_space(1))) void*)const_cast<void*>(g),
      (__attribute__((address_space(3))) void*)l, 16, 0, 0);
}

// ---------------- router: logits (fp64 acc), argmax, one-hot, x->bf16 ----------------
__global__ __launch_bounds__(256) void router_kernel(
    const float* __restrict__ x, const float* __restrict__ rw,
    const float* __restrict__ rb, float* __restrict__ oh,
    unsigned short* __restrict__ xb, int* __restrict__ idx,
    int* __restrict__ pos, int* __restrict__ counts)
{
  const int token = blockIdx.x * 4 + (threadIdx.x >> 6);
  const int lane = threadIdx.x & 63;
  const float* xrow = x + (size_t)token * DIN;
  double acc[NE];
#pragma unroll
  for (int e = 0; e < NE; ++e) acc[e] = 0.0;

#pragma unroll
  for (int j = 0; j < 4; ++j) {
    const int v4 = j * 64 + lane;                      // float4 index in row
    const float4 xv = ((const float4*)xrow)[v4];
    const float4* rwr = (const float4*)(rw + (size_t)v4 * 32);  // 4 rows x 8
#pragma unroll
    for (int c = 0; c < 4; ++c) {
      const float xs = (&xv.x)[c];
      const float4 w0 = rwr[c * 2 + 0];
      const float4 w1 = rwr[c * 2 + 1];
      acc[0] += (double)(xs * w0.x); acc[1] += (double)(xs * w0.y);
      acc[2] += (double)(xs * w0.z); acc[3] += (double)(xs * w0.w);
      acc[4] += (double)(xs * w1.x); acc[5] += (double)(xs * w1.y);
      acc[6] += (double)(xs * w1.z); acc[7] += (double)(xs * w1.w);
    }
    ushort4 us;
    us.x = f2bf(xv.x); us.y = f2bf(xv.y); us.z = f2bf(xv.z); us.w = f2bf(xv.w);
    ((ushort4*)(xb + (size_t)token * DIN))[v4] = us;
  }
#pragma unroll
  for (int off = 32; off > 0; off >>= 1)
#pragma unroll
    for (int e = 0; e < NE; ++e) acc[e] += __shfl_xor(acc[e], off, 64);

  if (lane == 0) {
    double best = -1e300; int be = 0;
#pragma unroll
    for (int e = 0; e < NE; ++e) {
      const double v = acc[e] + (double)rb[e];
      if (v > best) { best = v; be = e; }   // strict > == first-max (np argmax)
    }
    idx[token] = be;
    pos[token] = atomicAdd(&counts[be], 1);
    float* o = oh + (size_t)token * NE;
#pragma unroll
    for (int e = 0; e < NE; ++e) o[e] = (e == be) ? 1.f : 0.f;
  }
}

// ---------------- fp32 [K][N] -> bf16 [N][K] transpose-convert ----------------
__global__ __launch_bounds__(256) void transpose_bf16(
    const float* __restrict__ in, unsigned short* __restrict__ out, int K, int N)
{
  __shared__ float tile[64][65];
  const size_t mat = (size_t)blockIdx.z * (size_t)K * N;
  const int k0 = blockIdx.x * 64, n0 = blockIdx.y * 64;
  const int c = threadIdx.x & 63, r0 = threadIdx.x >> 6;
#pragma unroll
  for (int rr = 0; rr < 64; rr += 4)
    tile[rr + r0][c] = in[mat + (size_t)(k0 + rr + r0) * N + n0 + c];
  __syncthreads();
#pragma unroll
  for (int rr = 0; rr < 64; rr += 4) {
    const int n2 = rr + r0;
    out[mat + (size_t)(n0 + n2) * K + k0 + c] = f2bf(tile[c][n2]);
  }
}

// ---------------- tile schedule (single thread, trivial); M-tile = 256 ----------------
__global__ void slots_kernel(const int* __restrict__ counts, int* __restrict__ offsets,
                             int* __restrict__ slot_e, int* __restrict__ slot_g0,
                             int* __restrict__ slot_nr, int* __restrict__ nslots)
{
  int off = 0, s = 0;
  offsets[0] = 0;
  for (int e = 0; e < NE; ++e) {
    const int c = counts[e];
    for (int t = 0; t < c; t += 256) {
      slot_e[s] = e; slot_g0[s] = off + t;
      slot_nr[s] = (c - t < 256) ? (c - t) : 256;
      ++s;
    }
    off += c;
    offsets[e + 1] = off;
  }
  *nslots = s;
}

__global__ __launch_bounds__(256) void scatter_kernel(
    const int* __restrict__ idx, const int* __restrict__ pos,
    const int* __restrict__ offsets, int* __restrict__ perm)
{
  const int t = blockIdx.x * 256 + threadIdx.x;
  perm[offsets[idx[t]] + pos[t]] = t;
}

// ---------------- grouped expert GEMM: h[g] = x[perm[g]] @ W[e] + eb[e] ----------------
// BM=BN=256, BK=64; 512 threads = 8 waves (2M x 4N), per-wave 128x64 output.
// Rationale: 128^2 tiles demand 1.05 GB of tile feed (supply-limited at ~7 TB/s
// effective -> 440 TF wall, schedule-invariant per R0/R1/R2). 256^2 halves
// demand (AI 64 -> 128 FLOP/B).
// Per-thread loads per K-tile: A=4, B=4 (16B each). Derived-wait pipeline:
//   boundary(t): stage A(t+1) [4] -> buf^1; vmcnt(4) (= tile t's 8 oldest done,
//                A(t+1) in flight); s_barrier
//   P0: ds_read ks0 frags; stage B(t+1) [4]; barrier; lgkmcnt(0); setprio(1);
//       32 MFMA; setprio(0); barrier
//   P1: same for ks1, no stage.
// Never vmcnt(0) except final tile. Uniform load count (clamped A rows) keeps
// the vmcnt accounting valid at partial tiles.
__global__ __launch_bounds__(512) void expert_gemm(
    const unsigned short* __restrict__ xb, const unsigned short* __restrict__ Wt,
    const float* __restrict__ eb, const int* __restrict__ perm,
    const int* __restrict__ slot_e, const int* __restrict__ slot_g0,
    const int* __restrict__ slot_nr, const int* __restrict__ nslots,
    unsigned short* __restrict__ h)
{
  const int id = blockIdx.x;
  const int s = id >> 4;           // slot (M-tile of 256 tokens)
  const int ntile = id & 15;       // 16 N-tiles of 256
  if (s >= *nslots) return;
  const int e = slot_e[s];
  const int g0 = slot_g0[s];
  const int nr = slot_nr[s];
  const int n0 = ntile * 256;

  __shared__ __align__(16) unsigned short lsA[2][256 * 64];   // 64 KB
  __shared__ __align__(16) unsigned short lsB[2][256 * 64];   // 64 KB

  const int tid = threadIdx.x;
  const int w = tid >> 6, lane = tid & 63;
  const int rgrp = lane >> 3, cch = lane & 7;
  const int sw8 = (cch ^ rgrp) * 8;          // XOR-swizzled global k-chunk
  const int wr = w >> 2, wc = w & 3;         // wave -> (2M x 4N)
  const int quad = lane >> 4, l15 = lane & 15;

  // A row sources: row(sub) = sub*64 + w*8 + rgrp (clamped -> uniform count)
  const unsigned short* ap[4];
#pragma unroll
  for (int sub = 0; sub < 4; ++sub) {
    const int row = sub * 64 + w * 8 + rgrp;
    ap[sub] = xb + (size_t)perm[g0 + (row < nr ? row : 0)] * DIN + sw8;
  }
  const unsigned short* wbp = Wt + (size_t)e * DHID * DIN;
  const unsigned short* bp[4];
#pragma unroll
  for (int sub = 0; sub < 4; ++sub)
    bp[sub] = wbp + (size_t)(n0 + sub * 64 + w * 8 + rgrp) * DIN + sw8;

  f32x4 acc[8][4];
  const f32x4 z = {0.f, 0.f, 0.f, 0.f};
#pragma unroll
  for (int i = 0; i < 8; ++i)
#pragma unroll
    for (int j = 0; j < 4; ++j) acc[i][j] = z;

  auto stageA = [&](int db, int k0) {       // 4 loads/thread
#pragma unroll
    for (int sub = 0; sub < 4; ++sub)
      async16(ap[sub] + k0, &lsA[db][(sub * 64 + w * 8) * 64]);
  };
  auto stageB = [&](int db, int k0) {       // 4 loads/thread
#pragma unroll
    for (int sub = 0; sub < 4; ++sub)
      async16(bp[sub] + k0, &lsB[db][(sub * 64 + w * 8) * 64]);
  };

  auto phase = [&](int db, int ks, bool dostage, int k0n) {
    bf16x8 af[8], bfv[4];
    const int q = ks * 4 + quad;
#pragma unroll
    for (int i = 0; i < 8; ++i) {
      const int row = wr * 128 + i * 16 + l15;
      af[i] = *(const bf16x8*)&lsA[db][row * 64 + ((q ^ (row & 7)) << 3)];
    }
#pragma unroll
    for (int j = 0; j < 4; ++j) {
      const int row = wc * 64 + j * 16 + l15;
      bfv[j] = *(const bf16x8*)&lsB[db][row * 64 + ((q ^ (row & 7)) << 3)];
    }
    if (dostage) stageB(db ^ 1, k0n);
    __builtin_amdgcn_s_barrier();
    asm volatile("s_waitcnt lgkmcnt(0)" ::: "memory");
    __builtin_amdgcn_sched_barrier(0);           // rule #18: keep MFMA below wait
    __builtin_amdgcn_s_setprio(1);
#pragma unroll
    for (int i = 0; i < 8; ++i)
#pragma unroll
      for (int j = 0; j < 4; ++j)
        acc[i][j] = __builtin_amdgcn_mfma_f32_16x16x32_bf16(af[i], bfv[j], acc[i][j], 0, 0, 0);
    __builtin_amdgcn_s_setprio(0);
    __builtin_amdgcn_s_barrier();
  };

  auto tile = [&](int db, int t, bool notlast) {
    if (notlast) {
      stageA(db ^ 1, (t + 1) * 64);
      asm volatile("s_waitcnt vmcnt(4)" ::: "memory");
    } else {
      asm volatile("s_waitcnt vmcnt(0)" ::: "memory");
    }
    __builtin_amdgcn_s_barrier();
    phase(db, 0, notlast, (t + 1) * 64);
    phase(db, 1, false, 0);
  };

  stageA(0, 0);
  stageB(0, 0);                        // full tile 0: 8 loads
  constexpr int NT = DIN / 64;         // 16 (even)
  for (int t = 0; t < NT; t += 2) {
    tile(0, t, true);                  // t <= NT-2 -> t+1 always exists
    tile(1, t + 1, t + 2 < NT);
  }

#pragma unroll
  for (int j = 0; j < 4; ++j) {
    const int col = n0 + wc * 64 + j * 16 + l15;
    const float bias = eb[e * DHID + col];
#pragma unroll
    for (int i = 0; i < 8; ++i)
#pragma unroll
      for (int r2 = 0; r2 < 4; ++r2) {
        const int row = wr * 128 + i * 16 + quad * 4 + r2;  // C/D: row=(lane>>4)*4+reg
        if (row < nr)
          h[(size_t)(g0 + row) * DHID + col] = f2bf(acc[i][j][r2] + bias);
      }
  }
}

// ---------------- projection GEMM: out[perm[g]] = h[g] @ P + pb ----------------
// BM=256, BN=128 -> grid 8 ntiles x 32 mtiles = 256 blocks (1/CU).
// id = ntile*32 + mtile: A(h)-tile sharers (same mtile, 8 ntiles) at id stride
// 32 == 0 mod 8 -> same XCD -> h read ~once from HBM. Same derived-wait pipeline.
__global__ __launch_bounds__(512) void proj_gemm(
    const unsigned short* __restrict__ hm, const unsigned short* __restrict__ Pt,
    const float* __restrict__ pb, const int* __restrict__ perm,
    float* __restrict__ out)
{
  const int id = blockIdx.x;
  const int m0 = (id & 31) * 256;
  const int n0 = (id >> 5) * 128;

  __shared__ __align__(16) unsigned short lsA[2][256 * 64];
  __shared__ __align__(16) unsigned short lsB[2][128 * 64];

  const int tid = threadIdx.x;
  const int w = tid >> 6, lane = tid & 63;
  const int rgrp = lane >> 3, cch = lane & 7;
  const int sw8 = (cch ^ rgrp) * 8;
  const int wr = w >> 2, wc = w & 3;
  const int quad = lane >> 4, l15 = lane & 15;

  const unsigned short* ap[4];
#pragma unroll
  for (int hh = 0; hh < 2; ++hh)
#pragma unroll
    for (int l = 0; l < 2; ++l) {
      const int row = m0 + hh * 128 + l * 64 + w * 8 + rgrp;
      ap[hh * 2 + l] = hm + (size_t)row * DHID + sw8;
    }
  const unsigned short* bp[2];
#pragma unroll
  for (int hh = 0; hh < 2; ++hh)
    bp[hh] = Pt + (size_t)(n0 + hh * 64 + w * 8 + rgrp) * DHID + sw8;

  f32x4 acc[8][2];
  const f32x4 z = {0.f, 0.f, 0.f, 0.f};
#pragma unroll
  for (int i = 0; i < 8; ++i) { acc[i][0] = z; acc[i][1] = z; }

  auto stageA0 = [&](int db, int k0) {
    async16(ap[0] + k0, &lsA[db][(w * 8) * 64]);
    async16(ap[1] + k0, &lsA[db][(64 + w * 8) * 64]);
  };
  auto stageRest = [&](int db, int k0) {
    async16(ap[2] + k0, &lsA[db][(128 + w * 8) * 64]);
    async16(ap[3] + k0, &lsA[db][(192 + w * 8) * 64]);
    async16(bp[0] + k0, &lsB[db][(w * 8) * 64]);
    async16(bp[1] + k0, &lsB[db][(64 + w * 8) * 64]);
  };

  auto phase = [&](int db, int ks, bool dostage, int k0n) {
    bf16x8 af[8], bfv[2];
    const int q = ks * 4 + quad;
#pragma unroll
    for (int i = 0; i < 8; ++i) {
      const int row = wr * 128 + i * 16 + l15;
      af[i] = *(const bf16x8*)&lsA[db][row * 64 + ((q ^ (row & 7)) << 3)];
    }
#pragma unroll
    for (int j = 0; j < 2; ++j) {
      const int row = wc * 32 + j * 16 + l15;
      bfv[j] = *(const bf16x8*)&lsB[db][row * 64 + ((q ^ (row & 7)) << 3)];
    }
    if (dostage) stageRest(db ^ 1, k0n);
    __builtin_amdgcn_s_barrier();
    asm volatile("s_waitcnt lgkmcnt(0)" ::: "memory");
    __builtin_amdgcn_sched_barrier(0);
    __builtin_amdgcn_s_setprio(1);
#pragma unroll
    for (int i = 0; i < 8; ++i)
#pragma unroll
      for (int j = 0; j < 2; ++j)
        acc[i][j] = __builtin_amdgcn_mfma_f32_16x16x32_bf16(af[i], bfv[j], acc[i][j], 0, 0, 0);
    __builtin_amdgcn_s_setprio(0);
    __builtin_amdgcn_s_barrier();
  };

  auto tile = [&](int db, int t, bool notlast) {
    if (notlast) {
      stageA0(db ^ 1, (t + 1) * 64);
      asm volatile("s_waitcnt vmcnt(2)" ::: "memory");
    } else {
      asm volatile("s_waitcnt vmcnt(0)" ::: "memory");
    }
    __builtin_amdgcn_s_barrier();
    phase(db, 0, notlast, (t + 1) * 64);
    phase(db, 1, false, 0);
  };

  stageA0(0, 0);
  stageRest(0, 0);
  constexpr int NT = DHID / 64;        // 64 (even)
  for (int t = 0; t < NT; t += 2) {
    tile(0, t, true);
    tile(1, t + 1, t + 2 < NT);
  }

#pragma unroll
  for (int i = 0; i < 8; ++i)
#pragma unroll
    for (int r2 = 0; r2 < 4; ++r2) {
      const int row = m0 + wr * 128 + i * 16 + quad * 4 + r2;
      const int orow = perm[row];
#pragma unroll
      for (int j = 0; j < 2; ++j) {
        const int col = n0 + wc * 32 + j * 16 + l15;
        out[(size_t)orow * DOUT + col] = acc[i][j][r2] + pb[col];
      }
    }
}

extern "C" void kernel_launch(void* const* d_in, const int* in_sizes, int n_in,
                              void* d_out, int out_size, void* d_ws, size_t ws_size,
                              hipStream_t stream)
{
  const float* x  = (const float*)d_in[0];
  const float* rw = (const float*)d_in[1];
  const float* rb = (const float*)d_in[2];
  const float* ew = (const float*)d_in[3];
  const float* eb = (const float*)d_in[4];
  const float* pw = (const float*)d_in[5];
  const float* pb = (const float*)d_in[6];
  float* out = (float*)d_out;
  float* oh  = out + (size_t)B_TOK * DOUT;   // one-hot routing weights tail

  char* ws = (char*)d_ws;
  constexpr size_t OXB = 0;                                         // x bf16 [8192][1024]
  constexpr size_t OWT = OXB + (size_t)B_TOK * DIN * 2;             // W^T bf16 [8][4096][1024]
  constexpr size_t OPT = OWT + (size_t)NE * DHID * DIN * 2;         // P^T bf16 [1024][4096]
  constexpr size_t OH  = OPT + (size_t)DOUT * DHID * 2;             // h bf16 [8192][4096] (perm order)
  constexpr size_t OIDX = OH + (size_t)B_TOK * DHID * 2;
  constexpr size_t OPOS = OIDX + (size_t)B_TOK * 4;
  constexpr size_t OPRM = OPOS + (size_t)B_TOK * 4;
  constexpr size_t OCNT = OPRM + (size_t)B_TOK * 4;
  constexpr size_t OOFF = OCNT + 256;
  constexpr size_t OSE  = OOFF + 256;
  constexpr size_t OSG  = OSE + 512;
  constexpr size_t OSN  = OSG + 512;
  constexpr size_t ONS  = OSN + 512;
  constexpr size_t NEED = ONS + 512;

  // Workspace guard: fail cleanly (zeroed output) instead of faulting.
  if (ws_size < NEED) {
    hipMemsetAsync(d_out, 0, (size_t)out_size * 4, stream);
    return;
  }

  unsigned short* xb   = (unsigned short*)(ws + OXB);
  unsigned short* Wt   = (unsigned short*)(ws + OWT);
  unsigned short* Pt   = (unsigned short*)(ws + OPT);
  unsigned short* h    = (unsigned short*)(ws + OH);
  int* idx     = (int*)(ws + OIDX);
  int* pos     = (int*)(ws + OPOS);
  int* perm    = (int*)(ws + OPRM);
  int* counts  = (int*)(ws + OCNT);
  int* offsets = (int*)(ws + OOFF);
  int* slot_e  = (int*)(ws + OSE);
  int* slot_g0 = (int*)(ws + OSG);
  int* slot_nr = (int*)(ws + OSN);
  int* nslots  = (int*)(ws + ONS);

  hipMemsetAsync(counts, 0, 64, stream);
  router_kernel<<<B_TOK / 4, 256, 0, stream>>>(x, rw, rb, oh, xb, idx, pos, counts);
  transpose_bf16<<<dim3(DIN / 64, DHID / 64, NE), 256, 0, stream>>>(ew, Wt, DIN, DHID);
  transpose_bf16<<<dim3(DHID / 64, DOUT / 64, 1), 256, 0, stream>>>(pw, Pt, DHID, DOUT);
  slots_kernel<<<1, 1, 0, stream>>>(counts, offsets, slot_e, slot_g0, slot_nr, nslots);
  scatter_kernel<<<B_TOK / 256, 256, 0, stream>>>(idx, pos, offsets, perm);
  // 40 slot capacity (32 full 256-row tiles + up to 8 expert-boundary partials)
  expert_gemm<<<40 * 16, 512, 0, stream>>>(
      xb, Wt, eb, perm, slot_e, slot_g0, slot_nr, nslots, h);
  proj_gemm<<<(DOUT / 128) * (B_TOK / 256), 512, 0, stream>>>(h, Pt, pb, perm, out);
}

// Round 4
// 564.803 us; speedup vs baseline: 1.0681x; 1.0364x over previous
//
#include <hip/hip_runtime.h>
#include <stdint.h>

#define B_TOK 8192
#define DIN 1024
#define DHID 4096
#define DOUT 1024
#define NE 8

typedef __bf16 bf16x8 __attribute__((ext_vector_type(8)));
typedef float f32x4 __attribute__((ext_vector_type(4)));

__device__ __forceinline__ unsigned short f2bf(float f) {
  union { float f; unsigned u; } v; v.f = f;
  unsigned r = v.u + 0x7fffu + ((v.u >> 16) & 1u);  // RNE
  return (unsigned short)(r >> 16);
}

__device__ __forceinline__ void async16(const void* g, void* l) {
  __builtin_amdgcn_global_load_lds(
      (__attribute__((address_space(1))) void*)const_cast<void*>(g),
      (__attribute__((address_space(3))) void*)l, 16, 0, 0);
}

// ---------------- router: logits (fp64 acc), argmax, one-hot, x->bf16 ----------------
__global__ __launch_bounds__(256) void router_kernel(
    const float* __restrict__ x, const float* __restrict__ rw,
    const float* __restrict__ rb, float* __restrict__ oh,
    unsigned short* __restrict__ xb, int* __restrict__ idx,
    int* __restrict__ pos, int* __restrict__ counts)
{
  const int token = blockIdx.x * 4 + (threadIdx.x >> 6);
  const int lane = threadIdx.x & 63;
  const float* xrow = x + (size_t)token * DIN;
  double acc[NE];
#pragma unroll
  for (int e = 0; e < NE; ++e) acc[e] = 0.0;

#pragma unroll
  for (int j = 0; j < 4; ++j) {
    const int v4 = j * 64 + lane;                      // float4 index in row
    const float4 xv = ((const float4*)xrow)[v4];
    const float4* rwr = (const float4*)(rw + (size_t)v4 * 32);  // 4 rows x 8
#pragma unroll
    for (int c = 0; c < 4; ++c) {
      const float xs = (&xv.x)[c];
      const float4 w0 = rwr[c * 2 + 0];
      const float4 w1 = rwr[c * 2 + 1];
      acc[0] += (double)(xs * w0.x); acc[1] += (double)(xs * w0.y);
      acc[2] += (double)(xs * w0.z); acc[3] += (double)(xs * w0.w);
      acc[4] += (double)(xs * w1.x); acc[5] += (double)(xs * w1.y);
      acc[6] += (double)(xs * w1.z); acc[7] += (double)(xs * w1.w);
    }
    ushort4 us;
    us.x = f2bf(xv.x); us.y = f2bf(xv.y); us.z = f2bf(xv.z); us.w = f2bf(xv.w);
    ((ushort4*)(xb + (size_t)token * DIN))[v4] = us;
  }
#pragma unroll
  for (int off = 32; off > 0; off >>= 1)
#pragma unroll
    for (int e = 0; e < NE; ++e) acc[e] += __shfl_xor(acc[e], off, 64);

  if (lane == 0) {
    double best = -1e300; int be = 0;
#pragma unroll
    for (int e = 0; e < NE; ++e) {
      const double v = acc[e] + (double)rb[e];
      if (v > best) { best = v; be = e; }   // strict > == first-max (np argmax)
    }
    idx[token] = be;
    pos[token] = atomicAdd(&counts[be], 1);
    float* o = oh + (size_t)token * NE;
#pragma unroll
    for (int e = 0; e < NE; ++e) o[e] = (e == be) ? 1.f : 0.f;
  }
}

// ---------------- fp32 [K][N] -> bf16 [N][K] transpose-convert ----------------
__global__ __launch_bounds__(256) void transpose_bf16(
    const float* __restrict__ in, unsigned short* __restrict__ out, int K, int N)
{
  __shared__ float tile[64][65];
  const size_t mat = (size_t)blockIdx.z * (size_t)K * N;
  const int k0 = blockIdx.x * 64, n0 = blockIdx.y * 64;
  const int c = threadIdx.x & 63, r0 = threadIdx.x >> 6;
#pragma unroll
  for (int rr = 0; rr < 64; rr += 4)
    tile[rr + r0][c] = in[mat + (size_t)(k0 + rr + r0) * N + n0 + c];
  __syncthreads();
#pragma unroll
  for (int rr = 0; rr < 64; rr += 4) {
    const int n2 = rr + r0;
    out[mat + (size_t)(n0 + n2) * K + k0 + c] = f2bf(tile[c][n2]);
  }
}

// ---------------- tile schedule (single thread, trivial); M-tile = 256 ----------------
__global__ void slots_kernel(const int* __restrict__ counts, int* __restrict__ offsets,
                             int* __restrict__ slot_e, int* __restrict__ slot_g0,
                             int* __restrict__ slot_nr, int* __restrict__ nslots)
{
  int off = 0, s = 0;
  offsets[0] = 0;
  for (int e = 0; e < NE; ++e) {
    const int c = counts[e];
    for (int t = 0; t < c; t += 256) {
      slot_e[s] = e; slot_g0[s] = off + t;
      slot_nr[s] = (c - t < 256) ? (c - t) : 256;
      ++s;
    }
    off += c;
    offsets[e + 1] = off;
  }
  *nslots = s;
}

__global__ __launch_bounds__(256) void scatter_kernel(
    const int* __restrict__ idx, const int* __restrict__ pos,
    const int* __restrict__ offsets, int* __restrict__ perm)
{
  const int t = blockIdx.x * 256 + threadIdx.x;
  perm[offsets[idx[t]] + pos[t]] = t;
}

// ---------------- grouped expert GEMM: h[g] = x[perm[g]] @ W[e] + eb[e] ----------------
// BM=BN=256, BK=64; 512 threads = 8 waves (2M x 4N), per-wave 128x64 output.
// T3 "minimum 2-phase" recipe (catalog-verified 655-682 TF at this geometry,
// incl. grouped K=1024): per K-tile, ONE sync point.
//   for t:  STAGE(buf^1, t+1)   // issued first -> flies across whole tile
//           ds_read buf[cur] + 64 MFMA (compiler-scheduled, setprio(1) around)
//           __syncthreads()     // compiler emits vmcnt(0)+lgkm drain: t+1 ready
// Safety ledger: stage(buf^1) is WAR-safe (prev iteration's reads of buf^1
// retired before its barrier); reads of buf[cur] are RAW-safe (prev barrier's
// vmcnt(0) landed the staging). No inline asm, no sched_barrier: R1 showed
// pinning the scheduler costs (VALUBusy 14->30% for zero MFMA gain).
__global__ __launch_bounds__(512) void expert_gemm(
    const unsigned short* __restrict__ xb, const unsigned short* __restrict__ Wt,
    const float* __restrict__ eb, const int* __restrict__ perm,
    const int* __restrict__ slot_e, const int* __restrict__ slot_g0,
    const int* __restrict__ slot_nr, const int* __restrict__ nslots,
    unsigned short* __restrict__ h)
{
  const int id = blockIdx.x;
  const int s = id >> 4;           // slot (M-tile of 256 tokens)
  const int ntile = id & 15;       // 16 N-tiles of 256
  if (s >= *nslots) return;
  const int e = slot_e[s];
  const int g0 = slot_g0[s];
  const int nr = slot_nr[s];
  const int n0 = ntile * 256;

  __shared__ __align__(16) unsigned short lsA[2][256 * 64];   // 64 KB
  __shared__ __align__(16) unsigned short lsB[2][256 * 64];   // 64 KB

  const int tid = threadIdx.x;
  const int w = tid >> 6, lane = tid & 63;
  const int rgrp = lane >> 3, cch = lane & 7;
  const int sw8 = (cch ^ rgrp) * 8;          // XOR-swizzled global k-chunk
  const int wr = w >> 2, wc = w & 3;         // wave -> (2M x 4N)
  const int quad = lane >> 4, l15 = lane & 15;

  // A row sources: row(sub) = sub*64 + w*8 + rgrp (clamped -> no OOB)
  const unsigned short* ap[4];
#pragma unroll
  for (int sub = 0; sub < 4; ++sub) {
    const int row = sub * 64 + w * 8 + rgrp;
    ap[sub] = xb + (size_t)perm[g0 + (row < nr ? row : 0)] * DIN + sw8;
  }
  const unsigned short* wbp = Wt + (size_t)e * DHID * DIN;
  const unsigned short* bp[4];
#pragma unroll
  for (int sub = 0; sub < 4; ++sub)
    bp[sub] = wbp + (size_t)(n0 + sub * 64 + w * 8 + rgrp) * DIN + sw8;

  f32x4 acc[8][4];
  const f32x4 z = {0.f, 0.f, 0.f, 0.f};
#pragma unroll
  for (int i = 0; i < 8; ++i)
#pragma unroll
    for (int j = 0; j < 4; ++j) acc[i][j] = z;

  auto stage = [&](int db, int k0) {        // 8 loads/thread
#pragma unroll
    for (int sub = 0; sub < 4; ++sub) {
      async16(ap[sub] + k0, &lsA[db][(sub * 64 + w * 8) * 64]);
      async16(bp[sub] + k0, &lsB[db][(sub * 64 + w * 8) * 64]);
    }
  };

  stage(0, 0);
  __syncthreads();                          // tile 0 landed

  constexpr int NT = DIN / 64;              // 16
  for (int t = 0; t < NT; ++t) {
    const int cur = t & 1;
    if (t + 1 < NT) stage(cur ^ 1, (t + 1) * 64);   // flies across this tile

    __builtin_amdgcn_s_setprio(1);
#pragma unroll
    for (int ks = 0; ks < 2; ++ks) {
      const int q = ks * 4 + quad;
      bf16x8 af[8], bfv[4];
#pragma unroll
      for (int i = 0; i < 8; ++i) {
        const int row = wr * 128 + i * 16 + l15;
        af[i] = *(const bf16x8*)&lsA[cur][row * 64 + ((q ^ (row & 7)) << 3)];
      }
#pragma unroll
      for (int j = 0; j < 4; ++j) {
        const int row = wc * 64 + j * 16 + l15;
        bfv[j] = *(const bf16x8*)&lsB[cur][row * 64 + ((q ^ (row & 7)) << 3)];
      }
#pragma unroll
      for (int i = 0; i < 8; ++i)
#pragma unroll
        for (int j = 0; j < 4; ++j)
          acc[i][j] = __builtin_amdgcn_mfma_f32_16x16x32_bf16(af[i], bfv[j], acc[i][j], 0, 0, 0);
    }
    __builtin_amdgcn_s_setprio(0);

    __syncthreads();                        // drains vmcnt: tile t+1 ready
  }

  // Epilogue: j innermost so each row's 64 cols (128B line) are written
  // back-to-back (reduces partial-line write amplification seen in R3).
  float bias[4];
#pragma unroll
  for (int j = 0; j < 4; ++j)
    bias[j] = eb[e * DHID + n0 + wc * 64 + j * 16 + l15];
#pragma unroll
  for (int i = 0; i < 8; ++i)
#pragma unroll
    for (int r2 = 0; r2 < 4; ++r2) {
      const int row = wr * 128 + i * 16 + quad * 4 + r2;  // C/D: row=(lane>>4)*4+reg
      if (row < nr) {
        unsigned short* hr = h + (size_t)(g0 + row) * DHID + n0 + wc * 64;
#pragma unroll
        for (int j = 0; j < 4; ++j)
          hr[j * 16 + l15] = f2bf(acc[i][j][r2] + bias[j]);
      }
    }
}

// ---------------- projection GEMM: out[perm[g]] = h[g] @ P + pb ----------------
// BM=256, BN=128 -> grid 8 ntiles x 32 mtiles = 256 blocks (1/CU).
// id = ntile*32 + mtile: A(h)-tile sharers (same mtile, 8 ntiles) at id stride
// 32 == 0 mod 8 -> same XCD. Same minimum-2-phase recipe, 6 loads/thread/tile.
__global__ __launch_bounds__(512) void proj_gemm(
    const unsigned short* __restrict__ hm, const unsigned short* __restrict__ Pt,
    const float* __restrict__ pb, const int* __restrict__ perm,
    float* __restrict__ out)
{
  const int id = blockIdx.x;
  const int m0 = (id & 31) * 256;
  const int n0 = (id >> 5) * 128;

  __shared__ __align__(16) unsigned short lsA[2][256 * 64];   // 64 KB
  __shared__ __align__(16) unsigned short lsB[2][128 * 64];   // 32 KB

  const int tid = threadIdx.x;
  const int w = tid >> 6, lane = tid & 63;
  const int rgrp = lane >> 3, cch = lane & 7;
  const int sw8 = (cch ^ rgrp) * 8;
  const int wr = w >> 2, wc = w & 3;
  const int quad = lane >> 4, l15 = lane & 15;

  const unsigned short* ap[4];
#pragma unroll
  for (int sub = 0; sub < 4; ++sub) {
    const int row = m0 + sub * 64 + w * 8 + rgrp;
    ap[sub] = hm + (size_t)row * DHID + sw8;
  }
  const unsigned short* bp[2];
#pragma unroll
  for (int hh = 0; hh < 2; ++hh)
    bp[hh] = Pt + (size_t)(n0 + hh * 64 + w * 8 + rgrp) * DHID + sw8;

  f32x4 acc[8][2];
  const f32x4 z = {0.f, 0.f, 0.f, 0.f};
#pragma unroll
  for (int i = 0; i < 8; ++i) { acc[i][0] = z; acc[i][1] = z; }

  auto stage = [&](int db, int k0) {        // 6 loads/thread
#pragma unroll
    for (int sub = 0; sub < 4; ++sub)
      async16(ap[sub] + k0, &lsA[db][(sub * 64 + w * 8) * 64]);
#pragma unroll
    for (int hh = 0; hh < 2; ++hh)
      async16(bp[hh] + k0, &lsB[db][(hh * 64 + w * 8) * 64]);
  };

  stage(0, 0);
  __syncthreads();

  constexpr int NT = DHID / 64;             // 64
  for (int t = 0; t < NT; ++t) {
    const int cur = t & 1;
    if (t + 1 < NT) stage(cur ^ 1, (t + 1) * 64);

    __builtin_amdgcn_s_setprio(1);
#pragma unroll
    for (int ks = 0; ks < 2; ++ks) {
      const int q = ks * 4 + quad;
      bf16x8 af[8], bfv[2];
#pragma unroll
      for (int i = 0; i < 8; ++i) {
        const int row = wr * 128 + i * 16 + l15;
        af[i] = *(const bf16x8*)&lsA[cur][row * 64 + ((q ^ (row & 7)) << 3)];
      }
#pragma unroll
      for (int j = 0; j < 2; ++j) {
        const int row = wc * 32 + j * 16 + l15;
        bfv[j] = *(const bf16x8*)&lsB[cur][row * 64 + ((q ^ (row & 7)) << 3)];
      }
#pragma unroll
      for (int i = 0; i < 8; ++i)
#pragma unroll
        for (int j = 0; j < 2; ++j)
          acc[i][j] = __builtin_amdgcn_mfma_f32_16x16x32_bf16(af[i], bfv[j], acc[i][j], 0, 0, 0);
    }
    __builtin_amdgcn_s_setprio(0);

    __syncthreads();
  }

  float pbj[2];
#pragma unroll
  for (int j = 0; j < 2; ++j)
    pbj[j] = pb[n0 + wc * 32 + j * 16 + l15];
#pragma unroll
  for (int i = 0; i < 8; ++i)
#pragma unroll
    for (int r2 = 0; r2 < 4; ++r2) {
      const int row = m0 + wr * 128 + i * 16 + quad * 4 + r2;
      const int orow = perm[row];
      float* orp = out + (size_t)orow * DOUT + n0 + wc * 32;
#pragma unroll
      for (int j = 0; j < 2; ++j)
        orp[j * 16 + l15] = acc[i][j][r2] + pbj[j];
    }
}

extern "C" void kernel_launch(void* const* d_in, const int* in_sizes, int n_in,
                              void* d_out, int out_size, void* d_ws, size_t ws_size,
                              hipStream_t stream)
{
  const float* x  = (const float*)d_in[0];
  const float* rw = (const float*)d_in[1];
  const float* rb = (const float*)d_in[2];
  const float* ew = (const float*)d_in[3];
  const float* eb = (const float*)d_in[4];
  const float* pw = (const float*)d_in[5];
  const float* pb = (const float*)d_in[6];
  float* out = (float*)d_out;
  float* oh  = out + (size_t)B_TOK * DOUT;   // one-hot routing weights tail

  char* ws = (char*)d_ws;
  constexpr size_t OXB = 0;                                         // x bf16 [8192][1024]
  constexpr size_t OWT = OXB + (size_t)B_TOK * DIN * 2;             // W^T bf16 [8][4096][1024]
  constexpr size_t OPT = OWT + (size_t)NE * DHID * DIN * 2;         // P^T bf16 [1024][4096]
  constexpr size_t OH  = OPT + (size_t)DOUT * DHID * 2;             // h bf16 [8192][4096] (perm order)
  constexpr size_t OIDX = OH + (size_t)B_TOK * DHID * 2;
  constexpr size_t OPOS = OIDX + (size_t)B_TOK * 4;
  constexpr size_t OPRM = OPOS + (size_t)B_TOK * 4;
  constexpr size_t OCNT = OPRM + (size_t)B_TOK * 4;
  constexpr size_t OOFF = OCNT + 256;
  constexpr size_t OSE  = OOFF + 256;
  constexpr size_t OSG  = OSE + 512;
  constexpr size_t OSN  = OSG + 512;
  constexpr size_t ONS  = OSN + 512;
  constexpr size_t NEED = ONS + 512;

  // Workspace guard: fail cleanly (zeroed output) instead of faulting.
  if (ws_size < NEED) {
    hipMemsetAsync(d_out, 0, (size_t)out_size * 4, stream);
    return;
  }

  unsigned short* xb   = (unsigned short*)(ws + OXB);
  unsigned short* Wt   = (unsigned short*)(ws + OWT);
  unsigned short* Pt   = (unsigned short*)(ws + OPT);
  unsigned short* h    = (unsigned short*)(ws + OH);
  int* idx     = (int*)(ws + OIDX);
  int* pos     = (int*)(ws + OPOS);
  int* perm    = (int*)(ws + OPRM);
  int* counts  = (int*)(ws + OCNT);
  int* offsets = (int*)(ws + OOFF);
  int* slot_e  = (int*)(ws + OSE);
  int* slot_g0 = (int*)(ws + OSG);
  int* slot_nr = (int*)(ws + OSN);
  int* nslots  = (int*)(ws + ONS);

  hipMemsetAsync(counts, 0, 64, stream);
  router_kernel<<<B_TOK / 4, 256, 0, stream>>>(x, rw, rb, oh, xb, idx, pos, counts);
  transpose_bf16<<<dim3(DIN / 64, DHID / 64, NE), 256, 0, stream>>>(ew, Wt, DIN, DHID);
  transpose_bf16<<<dim3(DHID / 64, DOUT / 64, 1), 256, 0, stream>>>(pw, Pt, DHID, DOUT);
  slots_kernel<<<1, 1, 0, stream>>>(counts, offsets, slot_e, slot_g0, slot_nr, nslots);
  scatter_kernel<<<B_TOK / 256, 256, 0, stream>>>(idx, pos, offsets, perm);
  // 40 slot capacity (32 full 256-row tiles + up to 8 expert-boundary partials)
  expert_gemm<<<40 * 16, 512, 0, stream>>>(
      xb, Wt, eb, perm, slot_e, slot_g0, slot_nr, nslots, h);
  proj_gemm<<<(DOUT / 128) * (B_TOK / 256), 512, 0, stream>>>(h, Pt, pb, perm, out);
}